// Round 3
// baseline (422.160 us; speedup 1.0000x reference)
//
#include <hip/hip_runtime.h>

#define IC 256
#define OC 512
#define NB 32
#define NP 16
#define KTOT 65536   // k = i*256 + c
#define KSUB 128     // k per LDS g-slab

// ---------------- Kernel A: h[b][c][p] = relu(b1[c] + sum_i W1[c][i]*x[b][i][p])
// grid: NB*NP blocks, 256 threads (thread = c)
__global__ void kA(const float* __restrict__ x, const float* __restrict__ W1,
                   const float* __restrict__ b1, float* __restrict__ h) {
    int bp = blockIdx.x;
    int b = bp >> 4, p = bp & 15;
    int c = threadIdx.x;
    __shared__ float xs[IC];
    xs[c] = x[b * 4096 + c * 16 + p];
    __syncthreads();
    float acc = b1[c];
    const float* wrow = W1 + c * IC;
    #pragma unroll 8
    for (int i = 0; i < IC; i += 4) {
        float4 w = *(const float4*)(wrow + i);
        acc += w.x * xs[i] + w.y * xs[i + 1] + w.z * xs[i + 2] + w.w * xs[i + 3];
    }
    h[b * 4096 + c * 16 + p] = fmaxf(acc, 0.f);
}

// ---------------- Kernel B2: G2[b][i*256+c] = sum_p x[b][i][p]*h[b][c][p]; sx[b][i]
// grid: 256 blocks = (b 32, itile 4, chalf 2), 256 threads.
__global__ void kB2(const float* __restrict__ x, const float* __restrict__ h,
                    float* __restrict__ G2, float* __restrict__ sx) {
    int bid = blockIdx.x;
    int b = bid >> 3, it = (bid >> 1) & 3, ct = bid & 1;
    __shared__ float xT[16 * 64];     // [p][il]
    __shared__ float hs[128 * 16];    // [c_local][p]
    int tid = threadIdx.x;
    // stage x tile (64 i x 16 p), transposed
    {
        int il = tid >> 2, pq = tid & 3;
        float4 v = *(const float4*)(x + b * 4096 + (it * 64 + il) * 16 + pq * 4);
        xT[(pq * 4 + 0) * 64 + il] = v.x;
        xT[(pq * 4 + 1) * 64 + il] = v.y;
        xT[(pq * 4 + 2) * 64 + il] = v.z;
        xT[(pq * 4 + 3) * 64 + il] = v.w;
    }
    // stage h half-slab (128 c x 16 p), linear copy
    #pragma unroll
    for (int r = 0; r < 2; ++r) {
        int idx = r * 1024 + tid * 4;
        *(float4*)&hs[idx] = *(const float4*)(h + b * 4096 + ct * 2048 + idx);
    }
    __syncthreads();
    int w = tid >> 6;          // wave: c sub-slice
    int il = tid & 63;         // i lane
    float xr[16];
    #pragma unroll
    for (int p = 0; p < 16; ++p) xr[p] = xT[p * 64 + il];
    float* gbase = G2 + (size_t)b * KTOT + (size_t)(it * 64 + il) * 256 + ct * 128 + w * 32;
    #pragma unroll
    for (int c4 = 0; c4 < 8; ++c4) {
        float g4[4];
        #pragma unroll
        for (int cc = 0; cc < 4; ++cc) {
            int cl = w * 32 + c4 * 4 + cc;
            const float* hp = &hs[cl * 16];
            float4 h0 = *(const float4*)(hp);
            float4 h1 = *(const float4*)(hp + 4);
            float4 h2 = *(const float4*)(hp + 8);
            float4 h3 = *(const float4*)(hp + 12);
            g4[cc] = xr[0] * h0.x + xr[1] * h0.y + xr[2] * h0.z + xr[3] * h0.w
                   + xr[4] * h1.x + xr[5] * h1.y + xr[6] * h1.z + xr[7] * h1.w
                   + xr[8] * h2.x + xr[9] * h2.y + xr[10] * h2.z + xr[11] * h2.w
                   + xr[12] * h3.x + xr[13] * h3.y + xr[14] * h3.z + xr[15] * h3.w;
        }
        *(float4*)(gbase + c4 * 4) = make_float4(g4[0], g4[1], g4[2], g4[3]);
    }
    if (ct == 0 && tid < 64) {
        float s = 0.f;
        #pragma unroll
        for (int p = 0; p < 16; ++p) s += xr[p];
        sx[b * 256 + it * 64 + tid] = s;
    }
}

// ---------------- Kernel C3: partial[kc][b][o] = sum_{k in chunk} G2[b][k]*W2[o][k]
// grid: nkc blocks, 256 threads. Tile 32b x 512o, thread 8b x 8o.
// W2 read directly global->reg (L2 serves the 4x line reuse); g via 16 KB LDS slab.
__global__ __launch_bounds__(256, 2) void kC3(const float* __restrict__ W2,
        const float* __restrict__ G2, float* __restrict__ partial, int kchunk) {
    __shared__ float gs[KSUB * 32];   // [k_local][b]
    int tid = threadIdx.x;
    int tb = tid & 3;        // b = tb*8 + ii
    int to = tid >> 2;       // o = to*8 + jj
    int k0 = blockIdx.x * kchunk;
    float acc[8][8];
    #pragma unroll
    for (int ii = 0; ii < 8; ++ii)
        #pragma unroll
        for (int jj = 0; jj < 8; ++jj) acc[ii][jj] = 0.f;
    const float* wbase = W2 + (size_t)(to * 8) * KTOT + k0;

    for (int kc = 0; kc < kchunk; kc += KSUB) {
        __syncthreads();
        // stage gs[k][b] from G2[b][k0+kc .. +KSUB)
        {
            int sb = tid >> 3, q = tid & 7;
            const float* gsrc = G2 + (size_t)sb * KTOT + k0 + kc;
            #pragma unroll
            for (int pp = 0; pp < 4; ++pp) {
                int quad = q + pp * 8;
                float4 v = *(const float4*)(gsrc + quad * 4);
                int kl = quad * 4;
                gs[(kl + 0) * 32 + sb] = v.x;
                gs[(kl + 1) * 32 + sb] = v.y;
                gs[(kl + 2) * 32 + sb] = v.z;
                gs[(kl + 3) * 32 + sb] = v.w;
            }
        }
        __syncthreads();
        for (int ks = 0; ks < KSUB; ks += 8) {
            float wv[8][8];   // [jj][kk] -- fully unrolled, stays in VGPRs
            #pragma unroll
            for (int jj = 0; jj < 8; ++jj) {
                const float* wp = wbase + (size_t)jj * KTOT + kc + ks;
                *(float4*)&wv[jj][0] = *(const float4*)(wp);
                *(float4*)&wv[jj][4] = *(const float4*)(wp + 4);
            }
            #pragma unroll
            for (int kk = 0; kk < 8; ++kk) {
                float g8[8];
                *(float4*)&g8[0] = *(float4*)&gs[(ks + kk) * 32 + tb * 8];
                *(float4*)&g8[4] = *(float4*)&gs[(ks + kk) * 32 + tb * 8 + 4];
                #pragma unroll
                for (int ii = 0; ii < 8; ++ii)
                    #pragma unroll
                    for (int jj = 0; jj < 8; ++jj)
                        acc[ii][jj] += g8[ii] * wv[jj][kk];
            }
        }
    }
    float* pout = partial + (size_t)blockIdx.x * 16384;
    #pragma unroll
    for (int ii = 0; ii < 8; ++ii) {
        int b = tb * 8 + ii;
        *(float4*)(pout + b * 512 + to * 8)     = make_float4(acc[ii][0], acc[ii][1], acc[ii][2], acc[ii][3]);
        *(float4*)(pout + b * 512 + to * 8 + 4) = make_float4(acc[ii][4], acc[ii][5], acc[ii][6], acc[ii][7]);
    }
}

// ---------------- kBias: bias[b][o] = sum_i b2[o*256+i]*sx[b*256+i]
__global__ void kBias(const float* __restrict__ b2, const float* __restrict__ sx,
                      float* __restrict__ bias) {
    __shared__ float sxs[32 * 260];
    __shared__ float b2s[8 * 260];
    int tid = threadIdx.x;
    int o0 = blockIdx.x * 8;
    #pragma unroll
    for (int p = 0; p < 32; ++p) {
        int f = tid + p * 256;
        sxs[(f >> 8) * 260 + (f & 255)] = sx[f];
    }
    #pragma unroll
    for (int p = 0; p < 8; ++p) {
        int f = tid + p * 256;
        b2s[(f >> 8) * 260 + (f & 255)] = b2[(size_t)o0 * 256 + f];
    }
    __syncthreads();
    int b = tid >> 3, ol = tid & 7;
    float acc = 0.f;
    #pragma unroll 8
    for (int i = 0; i < 256; i += 4) {
        float4 sv = *(float4*)&sxs[b * 260 + i];
        float4 wv = *(float4*)&b2s[ol * 260 + i];
        acc += sv.x * wv.x + sv.y * wv.y + sv.z * wv.z + sv.w * wv.w;
    }
    bias[b * 512 + o0 + ol] = acc;
}

// ---------------- kRed: out[j] = sum_{kc} partial[kc][j] + bias[j]
__global__ void kRed(const float* __restrict__ partial, const float* __restrict__ bias,
                     float* __restrict__ out, int nkc) {
    __shared__ float red[256];
    int tid = threadIdx.x;
    int q = tid >> 6, jj = tid & 63;
    int j = blockIdx.x * 64 + jj;
    int per = nkc >> 2;
    float s = 0.f;
    for (int t = 0; t < per; ++t)
        s += partial[(size_t)(q * per + t) * 16384 + j];
    red[tid] = s;
    __syncthreads();
    if (tid < 64)
        out[j] = red[jj] + red[64 + jj] + red[128 + jj] + red[192 + jj] + bias[j];
}

extern "C" void kernel_launch(void* const* d_in, const int* in_sizes, int n_in,
                              void* d_out, int out_size, void* d_ws, size_t ws_size,
                              hipStream_t stream) {
    const float* x  = (const float*)d_in[0];
    const float* W1 = (const float*)d_in[1];
    const float* b1 = (const float*)d_in[2];
    const float* W2 = (const float*)d_in[3];
    const float* b2 = (const float*)d_in[4];
    // d_in[5] (Wa), d_in[6] (ba): dead code in the reference — unused.
    float* out = (float*)d_out;
    float* ws = (float*)d_ws;

    float* h       = ws;                 // 131072; dead after kB2 -> reused as bias
    float* sx      = ws + 131072;        // 8192
    float* G2      = ws + 139264;        // 2097152  [b][k]
    float* partial = ws + 2236416;       // nkc * 16384
    float* bias    = ws;                 // aliases h

    size_t avail = (ws_size / 4 > 2236416) ? ws_size / 4 - 2236416 : 0;
    int nkc = (avail >= (size_t)512 * 16384) ? 512 : 128;
    int kchunk = KTOT / nkc;

    kA<<<NB * NP, 256, 0, stream>>>(x, W1, b1, h);
    kB2<<<256, 256, 0, stream>>>(x, h, G2, sx);
    kBias<<<64, 256, 0, stream>>>(b2, sx, bias);
    kC3<<<nkc, 256, 0, stream>>>(W2, G2, partial, kchunk);
    kRed<<<256, 256, 0, stream>>>(partial, bias, out, nkc);
}

// Round 4
// 333.848 us; speedup vs baseline: 1.2645x; 1.2645x over previous
//
#include <hip/hip_runtime.h>

#define IC 256
#define OC 512
#define NB 32
#define NP 16
#define KTOT 65536   // k = i*256 + c

typedef __attribute__((ext_vector_type(8))) short bf16x8;
typedef __attribute__((ext_vector_type(4))) float f32x4;

__device__ __forceinline__ unsigned short f2bf(float f) {
    unsigned int u = __float_as_uint(f);
    u += 0x7fffu + ((u >> 16) & 1u);   // round-to-nearest-even
    return (unsigned short)(u >> 16);
}

// ---------------- Kernel A: h[b][c][p] = relu(b1[c] + sum_i W1[c][i]*x[b][i][p])
__global__ void kA(const float* __restrict__ x, const float* __restrict__ W1,
                   const float* __restrict__ b1, float* __restrict__ h) {
    int bp = blockIdx.x;
    int b = bp >> 4, p = bp & 15;
    int c = threadIdx.x;
    __shared__ float xs[IC];
    xs[c] = x[b * 4096 + c * 16 + p];
    __syncthreads();
    float acc = b1[c];
    const float* wrow = W1 + c * IC;
    #pragma unroll 8
    for (int i = 0; i < IC; i += 4) {
        float4 w = *(const float4*)(wrow + i);
        acc += w.x * xs[i] + w.y * xs[i + 1] + w.z * xs[i + 2] + w.w * xs[i + 3];
    }
    h[b * 4096 + c * 16 + p] = fmaxf(acc, 0.f);
}

// ---------------- Kernel B2: G2bf[b][i*256+c] = bf16( sum_p x[b][i][p]*h[b][c][p] )
// also sx[b][i]. grid: 256 blocks = (b 32, itile 4, chalf 2), 256 threads.
__global__ void kB2(const float* __restrict__ x, const float* __restrict__ h,
                    unsigned short* __restrict__ G2, float* __restrict__ sx) {
    int bid = blockIdx.x;
    int b = bid >> 3, it = (bid >> 1) & 3, ct = bid & 1;
    __shared__ float xT[16 * 64];     // [p][il]
    __shared__ float hs[128 * 16];    // [c_local][p]
    int tid = threadIdx.x;
    {
        int il = tid >> 2, pq = tid & 3;
        float4 v = *(const float4*)(x + b * 4096 + (it * 64 + il) * 16 + pq * 4);
        xT[(pq * 4 + 0) * 64 + il] = v.x;
        xT[(pq * 4 + 1) * 64 + il] = v.y;
        xT[(pq * 4 + 2) * 64 + il] = v.z;
        xT[(pq * 4 + 3) * 64 + il] = v.w;
    }
    #pragma unroll
    for (int r = 0; r < 2; ++r) {
        int idx = r * 1024 + tid * 4;
        *(float4*)&hs[idx] = *(const float4*)(h + b * 4096 + ct * 2048 + idx);
    }
    __syncthreads();
    int w = tid >> 6;
    int il = tid & 63;
    float xr[16];
    #pragma unroll
    for (int p = 0; p < 16; ++p) xr[p] = xT[p * 64 + il];
    unsigned short* gbase = G2 + (size_t)b * KTOT + (size_t)(it * 64 + il) * 256 + ct * 128 + w * 32;
    #pragma unroll
    for (int c4 = 0; c4 < 8; ++c4) {
        float g4[4];
        #pragma unroll
        for (int cc = 0; cc < 4; ++cc) {
            int cl = w * 32 + c4 * 4 + cc;
            const float* hp = &hs[cl * 16];
            float4 h0 = *(const float4*)(hp);
            float4 h1 = *(const float4*)(hp + 4);
            float4 h2 = *(const float4*)(hp + 8);
            float4 h3 = *(const float4*)(hp + 12);
            g4[cc] = xr[0] * h0.x + xr[1] * h0.y + xr[2] * h0.z + xr[3] * h0.w
                   + xr[4] * h1.x + xr[5] * h1.y + xr[6] * h1.z + xr[7] * h1.w
                   + xr[8] * h2.x + xr[9] * h2.y + xr[10] * h2.z + xr[11] * h2.w
                   + xr[12] * h3.x + xr[13] * h3.y + xr[14] * h3.z + xr[15] * h3.w;
        }
        ushort4 pk = make_ushort4(f2bf(g4[0]), f2bf(g4[1]), f2bf(g4[2]), f2bf(g4[3]));
        *(ushort4*)(gbase + c4 * 4) = pk;   // 8B store
    }
    if (ct == 0 && tid < 64) {
        float s = 0.f;
        #pragma unroll
        for (int p = 0; p < 16; ++p) s += xr[p];
        sx[b * 256 + it * 64 + tid] = s;
    }
}

// ---------------- Kernel C5 (MFMA, no LDS):
// partial[kc][b][o] = sum_{k in chunk} G2bf[b][k] * bf16(W2[o][k])
// grid: nkc blocks x 256 thr (4 waves). Wave w: o in [w*128,(w+1)*128), all 32 b.
// A-frag: G2bf[m=lane&15 (+16*mt)][k0+ks*32+quad*8+j]   (one 16B bf16 load)
// B-frag: W2 [n=lane&15 (+o0)]  [k0+ks*32+quad*8+j]     (two 16B fp32 loads + cvt)
// C/D:    row b=(lane>>4)*4+reg (+16*mt), col o=lane&15 (+o0)   [m89-verified]
__global__ __launch_bounds__(256, 2) void kC5(const float* __restrict__ W2,
        const unsigned short* __restrict__ G2, float* __restrict__ partial, int kchunk) {
    int kc = blockIdx.x;
    int tid = threadIdx.x;
    int lane = tid & 63;
    int n16 = lane & 15;
    int quad = lane >> 4;
    int o_base = (tid >> 6) * 128;

    f32x4 acc[8][2];
    #pragma unroll
    for (int nt = 0; nt < 8; ++nt) {
        acc[nt][0] = (f32x4)(0.f);
        acc[nt][1] = (f32x4)(0.f);
    }

    int kend = (kc + 1) * kchunk;
    for (int k0 = kc * kchunk; k0 < kend; k0 += 128) {
        // A-frags: 2 mt x 4 ks, bf16 direct (full-line coalesced: 4 quads = 64B/row)
        bf16x8 afrag[2][4];
        #pragma unroll
        for (int mt = 0; mt < 2; ++mt) {
            const unsigned short* ap = G2 + (size_t)(mt * 16 + n16) * KTOT + k0 + quad * 8;
            #pragma unroll
            for (int ks = 0; ks < 4; ++ks)
                afrag[mt][ks] = *(const bf16x8*)(ap + ks * 32);
        }
        // nt loop with one-ahead B prefetch
        float4 cur[8];
        {
            const float* wp = W2 + (size_t)(o_base + n16) * KTOT + k0 + quad * 8;
            #pragma unroll
            for (int ks = 0; ks < 4; ++ks) {
                cur[ks * 2]     = *(const float4*)(wp + ks * 32);
                cur[ks * 2 + 1] = *(const float4*)(wp + ks * 32 + 4);
            }
        }
        #pragma unroll
        for (int nt = 0; nt < 8; ++nt) {
            float4 nxt[8];
            if (nt < 7) {
                const float* wp = W2 + (size_t)(o_base + (nt + 1) * 16 + n16) * KTOT + k0 + quad * 8;
                #pragma unroll
                for (int ks = 0; ks < 4; ++ks) {
                    nxt[ks * 2]     = *(const float4*)(wp + ks * 32);
                    nxt[ks * 2 + 1] = *(const float4*)(wp + ks * 32 + 4);
                }
            }
            #pragma unroll
            for (int ks = 0; ks < 4; ++ks) {
                float4 lo = cur[ks * 2], hi = cur[ks * 2 + 1];
                union { bf16x8 v; unsigned short s[8]; } bu;
                bu.s[0] = f2bf(lo.x); bu.s[1] = f2bf(lo.y);
                bu.s[2] = f2bf(lo.z); bu.s[3] = f2bf(lo.w);
                bu.s[4] = f2bf(hi.x); bu.s[5] = f2bf(hi.y);
                bu.s[6] = f2bf(hi.z); bu.s[7] = f2bf(hi.w);
                acc[nt][0] = __builtin_amdgcn_mfma_f32_16x16x32_bf16(afrag[0][ks], bu.v, acc[nt][0], 0, 0, 0);
                acc[nt][1] = __builtin_amdgcn_mfma_f32_16x16x32_bf16(afrag[1][ks], bu.v, acc[nt][1], 0, 0, 0);
            }
            #pragma unroll
            for (int q = 0; q < 8; ++q) cur[q] = nxt[q];
        }
    }
    // store C/D
    float* pout = partial + (size_t)kc * 16384;
    #pragma unroll
    for (int nt = 0; nt < 8; ++nt) {
        int o = o_base + nt * 16 + n16;
        #pragma unroll
        for (int mt = 0; mt < 2; ++mt) {
            #pragma unroll
            for (int r = 0; r < 4; ++r) {
                int b = mt * 16 + quad * 4 + r;
                pout[b * 512 + o] = acc[nt][mt][r];
            }
        }
    }
}

// ---------------- kBias: bias[b][o] = sum_i b2[o*256+i]*sx[b*256+i]
__global__ void kBias(const float* __restrict__ b2, const float* __restrict__ sx,
                      float* __restrict__ bias) {
    __shared__ float sxs[32 * 260];
    __shared__ float b2s[8 * 260];
    int tid = threadIdx.x;
    int o0 = blockIdx.x * 8;
    #pragma unroll
    for (int p = 0; p < 32; ++p) {
        int f = tid + p * 256;
        sxs[(f >> 8) * 260 + (f & 255)] = sx[f];
    }
    #pragma unroll
    for (int p = 0; p < 8; ++p) {
        int f = tid + p * 256;
        b2s[(f >> 8) * 260 + (f & 255)] = b2[(size_t)o0 * 256 + f];
    }
    __syncthreads();
    int b = tid >> 3, ol = tid & 7;
    float acc = 0.f;
    #pragma unroll 8
    for (int i = 0; i < 256; i += 4) {
        float4 sv = *(float4*)&sxs[b * 260 + i];
        float4 wv = *(float4*)&b2s[ol * 260 + i];
        acc += sv.x * wv.x + sv.y * wv.y + sv.z * wv.z + sv.w * wv.w;
    }
    bias[b * 512 + o0 + ol] = acc;
}

// ---------------- kRed: out[j] = sum_{kc} partial[kc][j] + bias[j]
__global__ void kRed(const float* __restrict__ partial, const float* __restrict__ bias,
                     float* __restrict__ out, int nkc) {
    __shared__ float red[256];
    int tid = threadIdx.x;
    int q = tid >> 6, jj = tid & 63;
    int j = blockIdx.x * 64 + jj;
    int per = nkc >> 2;
    float s = 0.f;
    for (int t = 0; t < per; ++t)
        s += partial[(size_t)(q * per + t) * 16384 + j];
    red[tid] = s;
    __syncthreads();
    if (tid < 64)
        out[j] = red[jj] + red[64 + jj] + red[128 + jj] + red[192 + jj] + bias[j];
}

extern "C" void kernel_launch(void* const* d_in, const int* in_sizes, int n_in,
                              void* d_out, int out_size, void* d_ws, size_t ws_size,
                              hipStream_t stream) {
    const float* x  = (const float*)d_in[0];
    const float* W1 = (const float*)d_in[1];
    const float* b1 = (const float*)d_in[2];
    const float* W2 = (const float*)d_in[3];
    const float* b2 = (const float*)d_in[4];
    // d_in[5] (Wa), d_in[6] (ba): dead code in the reference — unused.
    float* out = (float*)d_out;
    float* ws = (float*)d_ws;

    float* h              = ws;                 // 131072 fl; dead after kB2 -> reused as bias
    float* sx             = ws + 131072;        // 8192 fl
    unsigned short* G2    = (unsigned short*)(ws + 139264);  // 2 MB bf16 [b][k]
    float* partial        = ws + 2236416;       // nkc * 16384 fl
    float* bias           = ws;                 // aliases h

    size_t avail = (ws_size / 4 > 2236416) ? ws_size / 4 - 2236416 : 0;
    int nkc = (avail >= (size_t)512 * 16384) ? 512 : 128;
    int kchunk = KTOT / nkc;

    kA<<<NB * NP, 256, 0, stream>>>(x, W1, b1, h);
    kB2<<<256, 256, 0, stream>>>(x, h, G2, sx);
    kBias<<<64, 256, 0, stream>>>(b2, sx, bias);
    kC5<<<nkc, 256, 0, stream>>>(W2, G2, partial, kchunk);
    kRed<<<256, 256, 0, stream>>>(partial, bias, out, nkc);
}